// Round 18
// baseline (380.606 us; speedup 1.0000x reference)
//
#include <hip/hip_runtime.h>
#include <hip/hip_bf16.h>
#include <stdint.h>

#define NROWS 65536   // B*S = 16*4096
#define DDIM  256
#define KCAND 4096
#define CAP   64      // per-row candidate list slots (R18: 48->64; n<=64 = 1 entry/lane)
#define MARGIN1 5.2e-4f // phase-1 collect margin (worst-case bound 4.9e-4)
#define MARGIN2 8e-4f   // phase-2 prune margin

#define ROWS_PB 128   // rows per phase-1 block

typedef __bf16 bf16x8 __attribute__((ext_vector_type(8)));
typedef float  f32x4  __attribute__((ext_vector_type(4)));
typedef unsigned int u32;
typedef unsigned long long u64;

__device__ __forceinline__ u32 f2bf_u(float f) {
    u32 u = __float_as_uint(f);
    u += 0x7fffu + ((u >> 16) & 1u);
    return u >> 16;
}
__device__ __forceinline__ u32 pack2(float lo, float hi) { return f2bf_u(lo) | (f2bf_u(hi) << 16); }
__device__ __forceinline__ u32 fkey(float f) {
    u32 u = __float_as_uint(f);
    return (u & 0x80000000u) ? ~u : (u | 0x80000000u);
}
__device__ __forceinline__ float funkey(u32 k) {
    u32 u = (k & 0x80000000u) ? (k ^ 0x80000000u) : ~k;
    return __uint_as_float(u);
}
__device__ __forceinline__ float vmax4(f32x4 v) {
    return fmaxf(fmaxf(v[0], v[1]), fmaxf(v[2], v[3]));
}

// np-semantics exact distance with PRECOMPUTED b = fl(sequential fmaf sum e^2):
// r = fl(fl(A + b) - acc), acc = sequential ascending-d fmaf(2x,e). Bit-identical
// to the scalar np order (HW-validated R7-R17).
__device__ __forceinline__ float exact_rb(const float* __restrict__ xr, float A,
                                          const float* __restrict__ er, float b) {
    float acc = 0.f;
    #pragma unroll 8
    for (int q = 0; q < DDIM / 4; ++q) {
        float4 e  = ((const float4*)er)[q];
        float4 xv = ((const float4*)xr)[q];
        acc = fmaf(2.0f * xv.x, e.x, acc);
        acc = fmaf(2.0f * xv.y, e.y, acc);
        acc = fmaf(2.0f * xv.z, e.z, acc);
        acc = fmaf(2.0f * xv.w, e.w, acc);
    }
    return (A + b) - acc;
}

// ---------------------------------------------------------------- bsum
// b_k = sequential ascending-d fmaf(e,e) chain — EXACT np order.
__launch_bounds__(256)
__global__ void bsum_k(const float* __restrict__ e, float* __restrict__ bsum) {
    int k = blockIdx.x * 256 + threadIdx.x;   // 16 blocks x 256 = 4096
    const float4* er = (const float4*)(e + (size_t)k * DDIM);
    float b = 0.f;
    #pragma unroll 8
    for (int q = 0; q < DDIM / 4; ++q) {
        float4 v = er[q];
        b = fmaf(v.x, v.x, b);
        b = fmaf(v.y, v.y, b);
        b = fmaf(v.z, v.z, b);
        b = fmaf(v.w, v.w, b);
    }
    bsum[k] = b;
}

// ---------------------------------------------------------------- convert
// ebf strip-major for SGPR+imm addressing in phase1:
//   frag(s,kc,u): 1KB block at offset ((s*8+kc)*4+u)*1024; lane L's 16B at +L*16
//   holds cand = s*64 + u*16 + (L&15), k = kc*32 + (L>>4)*8  (8 bf16).
__launch_bounds__(256)
__global__ void convert_e(const float* __restrict__ e, u32* __restrict__ ebf) {
    int T = blockIdx.x * blockDim.x + threadIdx.x;   // 131072 = 64 s * 8 kc * 4 u * 64 L
    int L = T & 63, u = (T >> 6) & 3, kc = (T >> 8) & 7, s = T >> 11;
    int cand = s * 64 + u * 16 + (L & 15);
    int k0 = kc * 32 + (L >> 4) * 8;
    const float4* src = (const float4*)(e + (size_t)cand * DDIM + k0);
    float4 a = src[0], b = src[1];
    uint4 o;
    o.x = pack2(a.x, a.y); o.y = pack2(a.z, a.w);
    o.z = pack2(b.x, b.y); o.w = pack2(b.z, b.w);
    ((uint4*)ebf)[T] = o;
}

// ---------------------------------------------------------------- phase 1
// ROUND-15/17 ARTIFACT VERBATIM (217us, session best) except the CAP constant.
// Frag-major x tile: frag(a,kc) = 1KB block at (a*8+kc)*1024; lane L's 16B at
// +L*16 holds x[a*16+(L&15)][kc*32+(L>>4)*8..+8]. Conflict-free, compile-time
// offsets. REGISTER WALL: acc = 128 AGPR; VGPR must stay <= 128 for 2
// blocks/CU -> (256,2) enforces. Do not touch structure.
__launch_bounds__(256, 2)
__global__ void phase1(const float* __restrict__ x, const u32* __restrict__ ebf,
                       u32* __restrict__ cnt, uint2* __restrict__ list) {
    __shared__ u32 lxd[16384];           // 64KB frag-major x tile
    __shared__ u32 rowBestK[ROWS_PB];    // fkey(row acc-max), monotone under atomicMax

    const int tid = threadIdx.x;
    const int rowBase = blockIdx.x * ROWS_PB;
    if (tid < ROWS_PB) rowBestK[tid] = 0x007FFFFFu;   // fkey(-inf)

    // stage x tile once: fp32 -> bf16, FRAG-MAJOR scatter
    {
        const float4* x4 = (const float4*)(x + (size_t)rowBase * DDIM);
        #pragma unroll
        for (int j = 0; j < 32; ++j) {
            int idx = j * 256 + tid;          // 0..8191 float4 chunks
            int r = idx >> 6, c4 = idx & 63;
            float4 v = x4[idx];
            int a = r >> 4, ln = r & 15;
            int kc = c4 >> 3, lq = (c4 & 7) >> 1;
            int dstb = (a * 8 + kc) * 1024 + (ln + lq * 16) * 16 + 8 * (c4 & 1);
            *(uint2*)((char*)lxd + dstb) = make_uint2(pack2(v.x, v.y), pack2(v.z, v.w));
        }
    }
    __syncthreads();

    const int L = tid & 63;
    const int w = __builtin_amdgcn_readfirstlane(tid >> 6);   // force SGPR
    const int lq = L >> 4, ln = L & 15;
    const int vL = L << 4;                                     // lane byte offset in frag

    const char* ebc_w = (const char*)ebf + (size_t)w * 32768;

    auto loadB = [&](int it_, int kc_, bf16x8* dst) {
        const char* kb = ebc_w + (size_t)it_ * 131072 + kc_ * 4096;
        #pragma unroll
        for (int u = 0; u < 4; ++u)
            dst[u] = *(const bf16x8*)(kb + u * 1024 + vL);
    };

    // fa: one VGPR address (lane base), all frag offsets compile-time (< 64KB)
    const char* pa = (const char*)lxd + vL;

    bf16x8 bb[2][4];
    f32x4 acc[8][4];
    const f32x4 Z4 = {0.f, 0.f, 0.f, 0.f};

    // ---- PRE-PASS: it=0 maxes only, seeds rowBestK ----
    loadB(0, 0, bb[0]);
    #pragma unroll
    for (int kc = 0; kc < 8; ++kc) {
        if (kc < 7) loadB(0, kc + 1, bb[(kc + 1) & 1]);
        #pragma unroll
        for (int a = 0; a < 8; ++a) {
            bf16x8 fa = *(const bf16x8*)(pa + (a * 8 + kc) * 1024);
            #pragma unroll
            for (int u = 0; u < 4; ++u)
                acc[a][u] = (kc == 0)
                    ? __builtin_amdgcn_mfma_f32_16x16x32_bf16(bb[0][u], fa, Z4, 0, 0, 0)
                    : __builtin_amdgcn_mfma_f32_16x16x32_bf16(bb[kc & 1][u], fa, acc[a][u], 0, 0, 0);
        }
    }
    #pragma unroll
    for (int a = 0; a < 8; ++a) {
        float lmax = fmaxf(fmaxf(vmax4(acc[a][0]), vmax4(acc[a][1])),
                           fmaxf(vmax4(acc[a][2]), vmax4(acc[a][3])));
        float m = fmaxf(lmax, __shfl_xor(lmax, 16, 64));
        m = fmaxf(m, __shfl_xor(m, 32, 64));
        if (lq == 0) atomicMax(&rowBestK[a * 16 + ln], fkey(m));
    }
    __syncthreads();   // seeds visible before any collection

    // ---- MAIN LOOP: it=0..15 with collection ----
    loadB(0, 0, bb[0]);   // re-load (L1/L2-hot)
    #pragma unroll 1
    for (int it = 0; it < 16; ++it) {
        // kc = 0 peeled: accumulator init via zero C-operand
        {
            loadB(it, 1, bb[1]);
            #pragma unroll
            for (int a = 0; a < 8; ++a) {
                bf16x8 fa = *(const bf16x8*)(pa + (a * 8) * 1024);
                #pragma unroll
                for (int u = 0; u < 4; ++u)
                    acc[a][u] = __builtin_amdgcn_mfma_f32_16x16x32_bf16(bb[0][u], fa, Z4, 0, 0, 0);
            }
        }
        #pragma unroll
        for (int kc = 1; kc < 8; ++kc) {
            int g = it * 8 + kc;
            if (g < 127) { int gn = g + 1; loadB(gn >> 3, gn & 7, bb[(kc + 1) & 1]); }
            #pragma unroll
            for (int a = 0; a < 8; ++a) {
                bf16x8 fa = *(const bf16x8*)(pa + (a * 8 + kc) * 1024);
                #pragma unroll
                for (int u = 0; u < 4; ++u)
                    acc[a][u] = __builtin_amdgcn_mfma_f32_16x16x32_bf16(bb[kc & 1][u], fa, acc[a][u], 0, 0, 0);
            }
        }

        // epilogue for this strip (cands strip*64 .. +64), row-in-lane layout
        int strip = it * 4 + w;
        u32 seen[8];
        #pragma unroll
        for (int a = 0; a < 8; ++a) seen[a] = rowBestK[a * 16 + ln];   // broadcast reads, stale OK

        #pragma unroll
        for (int a = 0; a < 8; ++a) {
            float lmax = fmaxf(fmaxf(vmax4(acc[a][0]), vmax4(acc[a][1])),
                               fmaxf(vmax4(acc[a][2]), vmax4(acc[a][3])));
            float m = fmaxf(lmax, __shfl_xor(lmax, 16, 64));
            m = fmaxf(m, __shfl_xor(m, 32, 64));
            if (lq == 0) atomicMax(&rowBestK[a * 16 + ln], fkey(m));   // fire-and-forget
            float eff  = fmaxf(m, funkey(seen[a]));   // own strip folded in via register
            float thrA = eff - 0.5f * MARGIN1;        // acc-space threshold
            if (__ballot(lmax >= thrA)) {             // usually nothing fires
                int c = 0;
                #pragma unroll
                for (int u = 0; u < 4; ++u)
                    #pragma unroll
                    for (int r = 0; r < 4; ++r)
                        c += (acc[a][u][r] >= thrA) ? 1 : 0;
                int p = c, t;
                t = __shfl_up(p, 16, 64); if (lq >= 1) p += t;
                t = __shfl_up(p, 32, 64); if (lq >= 2) p += t;
                int grow = rowBase + a * 16 + ln;
                u32 base = 0;
                if (lq == 3 && p > 0) base = atomicAdd(&cnt[grow], (u32)p);  // 16 distinct rows
                base = __shfl(base, 48 + ln, 64);     // broadcast from lq==3 lane of this row
                u32 pos = base + (u32)(p - c);
                #pragma unroll
                for (int u = 0; u < 4; ++u)
                    #pragma unroll
                    for (int r = 0; r < 4; ++r) {
                        float av = acc[a][u][r];
                        if (av >= thrA) {
                            if (pos < CAP)
                                list[(size_t)grow * CAP + pos] =
                                    make_uint2(__float_as_uint(-2.f * av),
                                               (u32)(strip * 64 + u * 16 + lq * 4 + r));
                            ++pos;
                        }
                    }
            }
        }
    }
}

// ---------------------------------------------------------------- phase 2
// R17 VERBATIM (logic identical; CAP=64 means n<=CAP still fits one entry per
// lane, so the survivor path is unchanged). n==1 / unique-margin-survivor fast
// paths; exact_rb (bsum-precomputed, np-bit-exact) for ties; full scan only
// for the (now rarer) n>64 overflow rows.
__launch_bounds__(256)
__global__ void phase2(const float* __restrict__ x, const float* __restrict__ emb,
                       const u32* __restrict__ cnt, const uint2* __restrict__ list,
                       const float* __restrict__ bsum,
                       float* __restrict__ outq, float* __restrict__ outp) {
    __shared__ float xs[4][DDIM];
    const int wid = threadIdx.x >> 6;
    const int row = blockIdx.x * 4 + wid;
    const int L   = threadIdx.x & 63;

    u32 n = cnt[row];
    uint2 e0 = list[(size_t)row * CAP];   // hoisted: independent of n (n>=1 always)
    u32 kstar;

    if (n == 1) {
        kstar = e0.y;                     // unique candidate: no rescue needed
    } else {
        bool scan_all = (n > CAP);
        bool resolved = false;
        float vv = INFINITY; u32 kk = 0;
        bool surv = false;
        if (!scan_all) {
            if (L < (int)n) {
                uint2 e = (L == 0) ? e0 : list[(size_t)row * CAP + L];
                vv = __uint_as_float(e.x); kk = e.y;
            }
            float mv = vv;
            #pragma unroll
            for (int o = 32; o; o >>= 1) mv = fminf(mv, __shfl_xor(mv, o, 64));
            surv = (L < (int)n) && (vv <= mv + MARGIN2);
            u64 bal = __ballot(surv);
            if (__popcll(bal) == 1) {          // unique margin-survivor = exact winner
                kstar = __shfl(kk, (int)(__ffsll(bal) - 1), 64);
                resolved = true;
            }
        }
        if (!resolved) {
            float4 v = ((const float4*)(x + (size_t)row * DDIM))[L];
            *(float4*)&xs[wid][L * 4] = v;
            double s = (double)v.x * v.x + (double)v.y * v.y + (double)v.z * v.z + (double)v.w * v.w;
            #pragma unroll
            for (int o = 32; o; o >>= 1) s += __shfl_xor(s, o, 64);
            float A = (float)s;

            u64 key = 0xFFFFFFFFFFFFFFFFull;
            if (!scan_all) {
                if (surv) {
                    float r = exact_rb(xs[wid], A, emb + (size_t)kk * DDIM, bsum[kk]);
                    key = ((u64)fkey(r) << 32) | (u64)kk;
                }
            } else {
                for (int c = 0; c < KCAND / 64; ++c) {
                    u32 k = (u32)(c * 64 + L);
                    float r = exact_rb(xs[wid], A, emb + (size_t)k * DDIM, bsum[k]);
                    u64 cand = ((u64)fkey(r) << 32) | (u64)k;
                    key = (cand < key) ? cand : key;
                }
            }
            #pragma unroll
            for (int o = 32; o; o >>= 1) {
                u64 other = __shfl_xor(key, o, 64);
                key = (other < key) ? other : key;
            }
            kstar = (u32)(key & 0xFFFFFFFFull);
        }
    }

    float4 q = ((const float4*)(emb + (size_t)kstar * DDIM))[L];
    ((float4*)(outq + (size_t)row * DDIM))[L] = q;
    if (L == 0) outp[row] = (float)kstar;
}

// ---------------------------------------------------------------- launch
extern "C" void kernel_launch(void* const* d_in, const int* in_sizes, int n_in,
                              void* d_out, int out_size, void* d_ws, size_t ws_size,
                              hipStream_t stream) {
    const float* x   = (const float*)d_in[0];   // [65536, 256] fp32
    const float* emb = (const float*)d_in[1];   // [4096, 256] fp32
    float* outq = (float*)d_out;                      // [65536,256]
    float* outp = outq + (size_t)NROWS * DDIM;        // [65536]

    char* ws = (char*)d_ws;
    u32*   ebf  = (u32*)ws;                           // 2 MB (strip-major bf16)
    u32*   cnt  = (u32*)(ws + (2u << 20));            // 256 KB @2MB
    float* bsum = (float*)(ws + (2u << 20) + (256u << 10));   // 16 KB
    uint2* list = (uint2*)(ws + (3u << 20));          // 32 MB (total 35 MB)

    hipMemsetAsync(cnt, 0, (size_t)NROWS * sizeof(u32), stream);
    convert_e<<<512, 256, 0, stream>>>(emb, ebf);
    bsum_k<<<KCAND / 256, 256, 0, stream>>>(emb, bsum);
    phase1<<<NROWS / ROWS_PB, 256, 0, stream>>>(x, ebf, cnt, list);
    phase2<<<NROWS / 4, 256, 0, stream>>>(x, emb, cnt, list, bsum, outq, outp);
}

// Round 19
// 377.355 us; speedup vs baseline: 1.0086x; 1.0086x over previous
//
#include <hip/hip_runtime.h>
#include <hip/hip_bf16.h>
#include <stdint.h>

#define NROWS 65536   // B*S = 16*4096
#define DDIM  256
#define KCAND 4096
#define CAP   48      // per-row candidate list slots (R17 session-best value)
#define MARGIN1 5.2e-4f // phase-1 collect margin (worst-case bound 4.9e-4)
#define MARGIN2 8e-4f   // phase-2 prune margin

#define ROWS_PB 128   // rows per phase-1 block

typedef __bf16 bf16x8 __attribute__((ext_vector_type(8)));
typedef float  f32x4  __attribute__((ext_vector_type(4)));
typedef unsigned int u32;
typedef unsigned long long u64;

__device__ __forceinline__ u32 f2bf_u(float f) {
    u32 u = __float_as_uint(f);
    u += 0x7fffu + ((u >> 16) & 1u);
    return u >> 16;
}
__device__ __forceinline__ u32 pack2(float lo, float hi) { return f2bf_u(lo) | (f2bf_u(hi) << 16); }
__device__ __forceinline__ u32 fkey(float f) {
    u32 u = __float_as_uint(f);
    return (u & 0x80000000u) ? ~u : (u | 0x80000000u);
}
__device__ __forceinline__ float funkey(u32 k) {
    u32 u = (k & 0x80000000u) ? (k ^ 0x80000000u) : ~k;
    return __uint_as_float(u);
}
__device__ __forceinline__ float vmax4(f32x4 v) {
    return fmaxf(fmaxf(v[0], v[1]), fmaxf(v[2], v[3]));
}

// np-semantics exact distance with PRECOMPUTED b = fl(sequential fmaf sum e^2):
// r = fl(fl(A + b) - acc), acc = sequential ascending-d fmaf(2x,e). Bit-identical
// to the scalar np order (HW-validated R7-R18).
__device__ __forceinline__ float exact_rb(const float* __restrict__ xr, float A,
                                          const float* __restrict__ er, float b) {
    float acc = 0.f;
    #pragma unroll 8
    for (int q = 0; q < DDIM / 4; ++q) {
        float4 e  = ((const float4*)er)[q];
        float4 xv = ((const float4*)xr)[q];
        acc = fmaf(2.0f * xv.x, e.x, acc);
        acc = fmaf(2.0f * xv.y, e.y, acc);
        acc = fmaf(2.0f * xv.z, e.z, acc);
        acc = fmaf(2.0f * xv.w, e.w, acc);
    }
    return (A + b) - acc;
}

// ---------------------------------------------------------------- bsum
// b_k = sequential ascending-d fmaf(e,e) chain — EXACT np order.
__launch_bounds__(256)
__global__ void bsum_k(const float* __restrict__ e, float* __restrict__ bsum) {
    int k = blockIdx.x * 256 + threadIdx.x;   // 16 blocks x 256 = 4096
    const float4* er = (const float4*)(e + (size_t)k * DDIM);
    float b = 0.f;
    #pragma unroll 8
    for (int q = 0; q < DDIM / 4; ++q) {
        float4 v = er[q];
        b = fmaf(v.x, v.x, b);
        b = fmaf(v.y, v.y, b);
        b = fmaf(v.z, v.z, b);
        b = fmaf(v.w, v.w, b);
    }
    bsum[k] = b;
}

// ---------------------------------------------------------------- convert
// ebf strip-major for SGPR+imm addressing in phase1:
//   frag(s,kc,u): 1KB block at offset ((s*8+kc)*4+u)*1024; lane L's 16B at +L*16
//   holds cand = s*64 + u*16 + (L&15), k = kc*32 + (L>>4)*8  (8 bf16).
__launch_bounds__(256)
__global__ void convert_e(const float* __restrict__ e, u32* __restrict__ ebf) {
    int T = blockIdx.x * blockDim.x + threadIdx.x;   // 131072 = 64 s * 8 kc * 4 u * 64 L
    int L = T & 63, u = (T >> 6) & 3, kc = (T >> 8) & 7, s = T >> 11;
    int cand = s * 64 + u * 16 + (L & 15);
    int k0 = kc * 32 + (L >> 4) * 8;
    const float4* src = (const float4*)(e + (size_t)cand * DDIM + k0);
    float4 a = src[0], b = src[1];
    uint4 o;
    o.x = pack2(a.x, a.y); o.y = pack2(a.z, a.w);
    o.z = pack2(b.x, b.y); o.w = pack2(b.z, b.w);
    ((uint4*)ebf)[T] = o;
}

// ---------------------------------------------------------------- phase 1
// ROUND-17 ARTIFACT VERBATIM (217us phase1 / 375.2us total — session best).
// Frag-major x tile: frag(a,kc) = 1KB block at (a*8+kc)*1024; lane L's 16B at
// +L*16 holds x[a*16+(L&15)][kc*32+(L>>4)*8..+8]. Conflict-free (1.8M),
// compile-time offsets. REGISTER WALL: acc = 128 AGPR; VGPR must stay <= 128
// for 2 blocks/CU -> (256,2) enforces. Do not touch structure.
__launch_bounds__(256, 2)
__global__ void phase1(const float* __restrict__ x, const u32* __restrict__ ebf,
                       u32* __restrict__ cnt, uint2* __restrict__ list) {
    __shared__ u32 lxd[16384];           // 64KB frag-major x tile
    __shared__ u32 rowBestK[ROWS_PB];    // fkey(row acc-max), monotone under atomicMax

    const int tid = threadIdx.x;
    const int rowBase = blockIdx.x * ROWS_PB;
    if (tid < ROWS_PB) rowBestK[tid] = 0x007FFFFFu;   // fkey(-inf)

    // stage x tile once: fp32 -> bf16, FRAG-MAJOR scatter
    {
        const float4* x4 = (const float4*)(x + (size_t)rowBase * DDIM);
        #pragma unroll
        for (int j = 0; j < 32; ++j) {
            int idx = j * 256 + tid;          // 0..8191 float4 chunks
            int r = idx >> 6, c4 = idx & 63;
            float4 v = x4[idx];
            int a = r >> 4, ln = r & 15;
            int kc = c4 >> 3, lq = (c4 & 7) >> 1;
            int dstb = (a * 8 + kc) * 1024 + (ln + lq * 16) * 16 + 8 * (c4 & 1);
            *(uint2*)((char*)lxd + dstb) = make_uint2(pack2(v.x, v.y), pack2(v.z, v.w));
        }
    }
    __syncthreads();

    const int L = tid & 63;
    const int w = __builtin_amdgcn_readfirstlane(tid >> 6);   // force SGPR
    const int lq = L >> 4, ln = L & 15;
    const int vL = L << 4;                                     // lane byte offset in frag

    const char* ebc_w = (const char*)ebf + (size_t)w * 32768;

    auto loadB = [&](int it_, int kc_, bf16x8* dst) {
        const char* kb = ebc_w + (size_t)it_ * 131072 + kc_ * 4096;
        #pragma unroll
        for (int u = 0; u < 4; ++u)
            dst[u] = *(const bf16x8*)(kb + u * 1024 + vL);
    };

    // fa: one VGPR address (lane base), all frag offsets compile-time (< 64KB)
    const char* pa = (const char*)lxd + vL;

    bf16x8 bb[2][4];
    f32x4 acc[8][4];
    const f32x4 Z4 = {0.f, 0.f, 0.f, 0.f};

    // ---- PRE-PASS: it=0 maxes only, seeds rowBestK ----
    loadB(0, 0, bb[0]);
    #pragma unroll
    for (int kc = 0; kc < 8; ++kc) {
        if (kc < 7) loadB(0, kc + 1, bb[(kc + 1) & 1]);
        #pragma unroll
        for (int a = 0; a < 8; ++a) {
            bf16x8 fa = *(const bf16x8*)(pa + (a * 8 + kc) * 1024);
            #pragma unroll
            for (int u = 0; u < 4; ++u)
                acc[a][u] = (kc == 0)
                    ? __builtin_amdgcn_mfma_f32_16x16x32_bf16(bb[0][u], fa, Z4, 0, 0, 0)
                    : __builtin_amdgcn_mfma_f32_16x16x32_bf16(bb[kc & 1][u], fa, acc[a][u], 0, 0, 0);
        }
    }
    #pragma unroll
    for (int a = 0; a < 8; ++a) {
        float lmax = fmaxf(fmaxf(vmax4(acc[a][0]), vmax4(acc[a][1])),
                           fmaxf(vmax4(acc[a][2]), vmax4(acc[a][3])));
        float m = fmaxf(lmax, __shfl_xor(lmax, 16, 64));
        m = fmaxf(m, __shfl_xor(m, 32, 64));
        if (lq == 0) atomicMax(&rowBestK[a * 16 + ln], fkey(m));
    }
    __syncthreads();   // seeds visible before any collection

    // ---- MAIN LOOP: it=0..15 with collection ----
    loadB(0, 0, bb[0]);   // re-load (L1/L2-hot)
    #pragma unroll 1
    for (int it = 0; it < 16; ++it) {
        // kc = 0 peeled: accumulator init via zero C-operand
        {
            loadB(it, 1, bb[1]);
            #pragma unroll
            for (int a = 0; a < 8; ++a) {
                bf16x8 fa = *(const bf16x8*)(pa + (a * 8) * 1024);
                #pragma unroll
                for (int u = 0; u < 4; ++u)
                    acc[a][u] = __builtin_amdgcn_mfma_f32_16x16x32_bf16(bb[0][u], fa, Z4, 0, 0, 0);
            }
        }
        #pragma unroll
        for (int kc = 1; kc < 8; ++kc) {
            int g = it * 8 + kc;
            if (g < 127) { int gn = g + 1; loadB(gn >> 3, gn & 7, bb[(kc + 1) & 1]); }
            #pragma unroll
            for (int a = 0; a < 8; ++a) {
                bf16x8 fa = *(const bf16x8*)(pa + (a * 8 + kc) * 1024);
                #pragma unroll
                for (int u = 0; u < 4; ++u)
                    acc[a][u] = __builtin_amdgcn_mfma_f32_16x16x32_bf16(bb[kc & 1][u], fa, acc[a][u], 0, 0, 0);
            }
        }

        // epilogue for this strip (cands strip*64 .. +64), row-in-lane layout
        int strip = it * 4 + w;
        u32 seen[8];
        #pragma unroll
        for (int a = 0; a < 8; ++a) seen[a] = rowBestK[a * 16 + ln];   // broadcast reads, stale OK

        #pragma unroll
        for (int a = 0; a < 8; ++a) {
            float lmax = fmaxf(fmaxf(vmax4(acc[a][0]), vmax4(acc[a][1])),
                               fmaxf(vmax4(acc[a][2]), vmax4(acc[a][3])));
            float m = fmaxf(lmax, __shfl_xor(lmax, 16, 64));
            m = fmaxf(m, __shfl_xor(m, 32, 64));
            if (lq == 0) atomicMax(&rowBestK[a * 16 + ln], fkey(m));   // fire-and-forget
            float eff  = fmaxf(m, funkey(seen[a]));   // own strip folded in via register
            float thrA = eff - 0.5f * MARGIN1;        // acc-space threshold
            if (__ballot(lmax >= thrA)) {             // usually nothing fires
                int c = 0;
                #pragma unroll
                for (int u = 0; u < 4; ++u)
                    #pragma unroll
                    for (int r = 0; r < 4; ++r)
                        c += (acc[a][u][r] >= thrA) ? 1 : 0;
                int p = c, t;
                t = __shfl_up(p, 16, 64); if (lq >= 1) p += t;
                t = __shfl_up(p, 32, 64); if (lq >= 2) p += t;
                int grow = rowBase + a * 16 + ln;
                u32 base = 0;
                if (lq == 3 && p > 0) base = atomicAdd(&cnt[grow], (u32)p);  // 16 distinct rows
                base = __shfl(base, 48 + ln, 64);     // broadcast from lq==3 lane of this row
                u32 pos = base + (u32)(p - c);
                #pragma unroll
                for (int u = 0; u < 4; ++u)
                    #pragma unroll
                    for (int r = 0; r < 4; ++r) {
                        float av = acc[a][u][r];
                        if (av >= thrA) {
                            if (pos < CAP)
                                list[(size_t)grow * CAP + pos] =
                                    make_uint2(__float_as_uint(-2.f * av),
                                               (u32)(strip * 64 + u * 16 + lq * 4 + r));
                            ++pos;
                        }
                    }
            }
        }
    }
}

// ---------------------------------------------------------------- phase 2
// R17 VERBATIM. First list entry hoisted (independent of n; n>=1 guaranteed).
// n==1 / unique-margin-survivor fast paths; exact_rb (bsum-precomputed,
// np-bit-exact) for ties; full scan for n>CAP overflow rows.
__launch_bounds__(256)
__global__ void phase2(const float* __restrict__ x, const float* __restrict__ emb,
                       const u32* __restrict__ cnt, const uint2* __restrict__ list,
                       const float* __restrict__ bsum,
                       float* __restrict__ outq, float* __restrict__ outp) {
    __shared__ float xs[4][DDIM];
    const int wid = threadIdx.x >> 6;
    const int row = blockIdx.x * 4 + wid;
    const int L   = threadIdx.x & 63;

    u32 n = cnt[row];
    uint2 e0 = list[(size_t)row * CAP];   // hoisted: independent of n
    u32 kstar;

    if (n == 1) {
        kstar = e0.y;                     // unique candidate: no rescue needed
    } else {
        bool scan_all = (n > CAP);
        bool resolved = false;
        float vv = INFINITY; u32 kk = 0;
        bool surv = false;
        if (!scan_all) {
            if (L < (int)n) {
                uint2 e = (L == 0) ? e0 : list[(size_t)row * CAP + L];
                vv = __uint_as_float(e.x); kk = e.y;
            }
            float mv = vv;
            #pragma unroll
            for (int o = 32; o; o >>= 1) mv = fminf(mv, __shfl_xor(mv, o, 64));
            surv = (L < (int)n) && (vv <= mv + MARGIN2);
            u64 bal = __ballot(surv);
            if (__popcll(bal) == 1) {          // unique margin-survivor = exact winner
                kstar = __shfl(kk, (int)(__ffsll(bal) - 1), 64);
                resolved = true;
            }
        }
        if (!resolved) {
            float4 v = ((const float4*)(x + (size_t)row * DDIM))[L];
            *(float4*)&xs[wid][L * 4] = v;
            double s = (double)v.x * v.x + (double)v.y * v.y + (double)v.z * v.z + (double)v.w * v.w;
            #pragma unroll
            for (int o = 32; o; o >>= 1) s += __shfl_xor(s, o, 64);
            float A = (float)s;

            u64 key = 0xFFFFFFFFFFFFFFFFull;
            if (!scan_all) {
                if (surv) {
                    float r = exact_rb(xs[wid], A, emb + (size_t)kk * DDIM, bsum[kk]);
                    key = ((u64)fkey(r) << 32) | (u64)kk;
                }
            } else {
                for (int c = 0; c < KCAND / 64; ++c) {
                    u32 k = (u32)(c * 64 + L);
                    float r = exact_rb(xs[wid], A, emb + (size_t)k * DDIM, bsum[k]);
                    u64 cand = ((u64)fkey(r) << 32) | (u64)k;
                    key = (cand < key) ? cand : key;
                }
            }
            #pragma unroll
            for (int o = 32; o; o >>= 1) {
                u64 other = __shfl_xor(key, o, 64);
                key = (other < key) ? other : key;
            }
            kstar = (u32)(key & 0xFFFFFFFFull);
        }
    }

    float4 q = ((const float4*)(emb + (size_t)kstar * DDIM))[L];
    ((float4*)(outq + (size_t)row * DDIM))[L] = q;
    if (L == 0) outp[row] = (float)kstar;
}

// ---------------------------------------------------------------- launch
extern "C" void kernel_launch(void* const* d_in, const int* in_sizes, int n_in,
                              void* d_out, int out_size, void* d_ws, size_t ws_size,
                              hipStream_t stream) {
    const float* x   = (const float*)d_in[0];   // [65536, 256] fp32
    const float* emb = (const float*)d_in[1];   // [4096, 256] fp32
    float* outq = (float*)d_out;                      // [65536,256]
    float* outp = outq + (size_t)NROWS * DDIM;        // [65536]

    char* ws = (char*)d_ws;
    u32*   ebf  = (u32*)ws;                           // 2 MB (strip-major bf16)
    u32*   cnt  = (u32*)(ws + (2u << 20));            // 256 KB @2MB
    float* bsum = (float*)(ws + (2u << 20) + (256u << 10));   // 16 KB
    uint2* list = (uint2*)(ws + (3u << 20));          // 24 MB (total 27 MB)

    hipMemsetAsync(cnt, 0, (size_t)NROWS * sizeof(u32), stream);
    convert_e<<<512, 256, 0, stream>>>(emb, ebf);
    bsum_k<<<KCAND / 256, 256, 0, stream>>>(emb, bsum);
    phase1<<<NROWS / ROWS_PB, 256, 0, stream>>>(x, ebf, cnt, list);
    phase2<<<NROWS / 4, 256, 0, stream>>>(x, emb, cnt, list, bsum, outq, outp);
}

// Round 20
// 375.238 us; speedup vs baseline: 1.0143x; 1.0056x over previous
//
#include <hip/hip_runtime.h>
#include <hip/hip_bf16.h>
#include <stdint.h>

#define NROWS 65536   // B*S = 16*4096
#define DDIM  256
#define KCAND 4096
#define CAP   48      // per-row candidate list slots (session-best value)
#define MARGIN1 5.2e-4f // phase-1 collect margin (worst-case bound 4.9e-4)
#define MARGIN2 8e-4f   // phase-2 prune margin

#define ROWS_PB 128   // rows per phase-1 block

typedef __bf16 bf16x8 __attribute__((ext_vector_type(8)));
typedef float  f32x4  __attribute__((ext_vector_type(4)));
typedef unsigned int u32;
typedef unsigned long long u64;

__device__ __forceinline__ u32 f2bf_u(float f) {
    u32 u = __float_as_uint(f);
    u += 0x7fffu + ((u >> 16) & 1u);
    return u >> 16;
}
__device__ __forceinline__ u32 pack2(float lo, float hi) { return f2bf_u(lo) | (f2bf_u(hi) << 16); }
__device__ __forceinline__ u32 fkey(float f) {
    u32 u = __float_as_uint(f);
    return (u & 0x80000000u) ? ~u : (u | 0x80000000u);
}
__device__ __forceinline__ float funkey(u32 k) {
    u32 u = (k & 0x80000000u) ? (k ^ 0x80000000u) : ~k;
    return __uint_as_float(u);
}
__device__ __forceinline__ float vmax4(f32x4 v) {
    return fmaxf(fmaxf(v[0], v[1]), fmaxf(v[2], v[3]));
}

// np-semantics exact distance with PRECOMPUTED b = fl(sequential fmaf sum e^2):
// r = fl(fl(A + b) - acc), acc = sequential ascending-d fmaf(2x,e). Bit-identical
// to the scalar np order (HW-validated R7-R19).
__device__ __forceinline__ float exact_rb(const float* __restrict__ xr, float A,
                                          const float* __restrict__ er, float b) {
    float acc = 0.f;
    #pragma unroll 8
    for (int q = 0; q < DDIM / 4; ++q) {
        float4 e  = ((const float4*)er)[q];
        float4 xv = ((const float4*)xr)[q];
        acc = fmaf(2.0f * xv.x, e.x, acc);
        acc = fmaf(2.0f * xv.y, e.y, acc);
        acc = fmaf(2.0f * xv.z, e.z, acc);
        acc = fmaf(2.0f * xv.w, e.w, acc);
    }
    return (A + b) - acc;
}

// ---------------------------------------------------------------- bsum
// b_k = sequential ascending-d fmaf(e,e) chain — EXACT np order.
__launch_bounds__(256)
__global__ void bsum_k(const float* __restrict__ e, float* __restrict__ bsum) {
    int k = blockIdx.x * 256 + threadIdx.x;   // 16 blocks x 256 = 4096
    const float4* er = (const float4*)(e + (size_t)k * DDIM);
    float b = 0.f;
    #pragma unroll 8
    for (int q = 0; q < DDIM / 4; ++q) {
        float4 v = er[q];
        b = fmaf(v.x, v.x, b);
        b = fmaf(v.y, v.y, b);
        b = fmaf(v.z, v.z, b);
        b = fmaf(v.w, v.w, b);
    }
    bsum[k] = b;
}

// ---------------------------------------------------------------- convert
// ebf strip-major for SGPR+imm addressing in phase1:
//   frag(s,kc,u): 1KB block at offset ((s*8+kc)*4+u)*1024; lane L's 16B at +L*16
//   holds cand = s*64 + u*16 + (L&15), k = kc*32 + (L>>4)*8  (8 bf16).
__launch_bounds__(256)
__global__ void convert_e(const float* __restrict__ e, u32* __restrict__ ebf) {
    int T = blockIdx.x * blockDim.x + threadIdx.x;   // 131072 = 64 s * 8 kc * 4 u * 64 L
    int L = T & 63, u = (T >> 6) & 3, kc = (T >> 8) & 7, s = T >> 11;
    int cand = s * 64 + u * 16 + (L & 15);
    int k0 = kc * 32 + (L >> 4) * 8;
    const float4* src = (const float4*)(e + (size_t)cand * DDIM + k0);
    float4 a = src[0], b = src[1];
    uint4 o;
    o.x = pack2(a.x, a.y); o.y = pack2(a.z, a.w);
    o.z = pack2(b.x, b.y); o.w = pack2(b.z, b.w);
    ((uint4*)ebf)[T] = o;
}

// ---------------------------------------------------------------- phase 1
// ROUND-17/19 ARTIFACT (217us phase1 / 375us total — session best) + in-kernel
// cnt zeroing (replaces the memset dispatch): cnt rows are BLOCK-EXCLUSIVE
// (all atomicAdds target this block's own 128 rows), so a plain store before
// the first __syncthreads (vmcnt drain to this XCD's L2 = the atomic
// coherence point) is safe. Saves one graph dispatch + 256KB memset.
// Frag-major x tile: frag(a,kc) = 1KB block at (a*8+kc)*1024; lane L's 16B at
// +L*16 holds x[a*16+(L&15)][kc*32+(L>>4)*8..+8]. Conflict-free (1.8M),
// compile-time offsets. REGISTER WALL: acc = 128 AGPR; VGPR must stay <= 128
// for 2 blocks/CU -> (256,2) enforces. Do not touch structure.
__launch_bounds__(256, 2)
__global__ void phase1(const float* __restrict__ x, const u32* __restrict__ ebf,
                       u32* __restrict__ cnt, uint2* __restrict__ list) {
    __shared__ u32 lxd[16384];           // 64KB frag-major x tile
    __shared__ u32 rowBestK[ROWS_PB];    // fkey(row acc-max), monotone under atomicMax

    const int tid = threadIdx.x;
    const int rowBase = blockIdx.x * ROWS_PB;
    if (tid < ROWS_PB) {
        rowBestK[tid] = 0x007FFFFFu;     // fkey(-inf)
        cnt[rowBase + tid] = 0;          // block-exclusive rows: self-zeroed
    }

    // stage x tile once: fp32 -> bf16, FRAG-MAJOR scatter
    {
        const float4* x4 = (const float4*)(x + (size_t)rowBase * DDIM);
        #pragma unroll
        for (int j = 0; j < 32; ++j) {
            int idx = j * 256 + tid;          // 0..8191 float4 chunks
            int r = idx >> 6, c4 = idx & 63;
            float4 v = x4[idx];
            int a = r >> 4, ln = r & 15;
            int kc = c4 >> 3, lq = (c4 & 7) >> 1;
            int dstb = (a * 8 + kc) * 1024 + (ln + lq * 16) * 16 + 8 * (c4 & 1);
            *(uint2*)((char*)lxd + dstb) = make_uint2(pack2(v.x, v.y), pack2(v.z, v.w));
        }
    }
    __syncthreads();

    const int L = tid & 63;
    const int w = __builtin_amdgcn_readfirstlane(tid >> 6);   // force SGPR
    const int lq = L >> 4, ln = L & 15;
    const int vL = L << 4;                                     // lane byte offset in frag

    const char* ebc_w = (const char*)ebf + (size_t)w * 32768;

    auto loadB = [&](int it_, int kc_, bf16x8* dst) {
        const char* kb = ebc_w + (size_t)it_ * 131072 + kc_ * 4096;
        #pragma unroll
        for (int u = 0; u < 4; ++u)
            dst[u] = *(const bf16x8*)(kb + u * 1024 + vL);
    };

    // fa: one VGPR address (lane base), all frag offsets compile-time (< 64KB)
    const char* pa = (const char*)lxd + vL;

    bf16x8 bb[2][4];
    f32x4 acc[8][4];
    const f32x4 Z4 = {0.f, 0.f, 0.f, 0.f};

    // ---- PRE-PASS: it=0 maxes only, seeds rowBestK ----
    loadB(0, 0, bb[0]);
    #pragma unroll
    for (int kc = 0; kc < 8; ++kc) {
        if (kc < 7) loadB(0, kc + 1, bb[(kc + 1) & 1]);
        #pragma unroll
        for (int a = 0; a < 8; ++a) {
            bf16x8 fa = *(const bf16x8*)(pa + (a * 8 + kc) * 1024);
            #pragma unroll
            for (int u = 0; u < 4; ++u)
                acc[a][u] = (kc == 0)
                    ? __builtin_amdgcn_mfma_f32_16x16x32_bf16(bb[0][u], fa, Z4, 0, 0, 0)
                    : __builtin_amdgcn_mfma_f32_16x16x32_bf16(bb[kc & 1][u], fa, acc[a][u], 0, 0, 0);
        }
    }
    #pragma unroll
    for (int a = 0; a < 8; ++a) {
        float lmax = fmaxf(fmaxf(vmax4(acc[a][0]), vmax4(acc[a][1])),
                           fmaxf(vmax4(acc[a][2]), vmax4(acc[a][3])));
        float m = fmaxf(lmax, __shfl_xor(lmax, 16, 64));
        m = fmaxf(m, __shfl_xor(m, 32, 64));
        if (lq == 0) atomicMax(&rowBestK[a * 16 + ln], fkey(m));
    }
    __syncthreads();   // seeds visible before any collection

    // ---- MAIN LOOP: it=0..15 with collection ----
    loadB(0, 0, bb[0]);   // re-load (L1/L2-hot)
    #pragma unroll 1
    for (int it = 0; it < 16; ++it) {
        // kc = 0 peeled: accumulator init via zero C-operand
        {
            loadB(it, 1, bb[1]);
            #pragma unroll
            for (int a = 0; a < 8; ++a) {
                bf16x8 fa = *(const bf16x8*)(pa + (a * 8) * 1024);
                #pragma unroll
                for (int u = 0; u < 4; ++u)
                    acc[a][u] = __builtin_amdgcn_mfma_f32_16x16x32_bf16(bb[0][u], fa, Z4, 0, 0, 0);
            }
        }
        #pragma unroll
        for (int kc = 1; kc < 8; ++kc) {
            int g = it * 8 + kc;
            if (g < 127) { int gn = g + 1; loadB(gn >> 3, gn & 7, bb[(kc + 1) & 1]); }
            #pragma unroll
            for (int a = 0; a < 8; ++a) {
                bf16x8 fa = *(const bf16x8*)(pa + (a * 8 + kc) * 1024);
                #pragma unroll
                for (int u = 0; u < 4; ++u)
                    acc[a][u] = __builtin_amdgcn_mfma_f32_16x16x32_bf16(bb[kc & 1][u], fa, acc[a][u], 0, 0, 0);
            }
        }

        // epilogue for this strip (cands strip*64 .. +64), row-in-lane layout
        int strip = it * 4 + w;
        u32 seen[8];
        #pragma unroll
        for (int a = 0; a < 8; ++a) seen[a] = rowBestK[a * 16 + ln];   // broadcast reads, stale OK

        #pragma unroll
        for (int a = 0; a < 8; ++a) {
            float lmax = fmaxf(fmaxf(vmax4(acc[a][0]), vmax4(acc[a][1])),
                               fmaxf(vmax4(acc[a][2]), vmax4(acc[a][3])));
            float m = fmaxf(lmax, __shfl_xor(lmax, 16, 64));
            m = fmaxf(m, __shfl_xor(m, 32, 64));
            if (lq == 0) atomicMax(&rowBestK[a * 16 + ln], fkey(m));   // fire-and-forget
            float eff  = fmaxf(m, funkey(seen[a]));   // own strip folded in via register
            float thrA = eff - 0.5f * MARGIN1;        // acc-space threshold
            if (__ballot(lmax >= thrA)) {             // usually nothing fires
                int c = 0;
                #pragma unroll
                for (int u = 0; u < 4; ++u)
                    #pragma unroll
                    for (int r = 0; r < 4; ++r)
                        c += (acc[a][u][r] >= thrA) ? 1 : 0;
                int p = c, t;
                t = __shfl_up(p, 16, 64); if (lq >= 1) p += t;
                t = __shfl_up(p, 32, 64); if (lq >= 2) p += t;
                int grow = rowBase + a * 16 + ln;
                u32 base = 0;
                if (lq == 3 && p > 0) base = atomicAdd(&cnt[grow], (u32)p);  // 16 distinct rows
                base = __shfl(base, 48 + ln, 64);     // broadcast from lq==3 lane of this row
                u32 pos = base + (u32)(p - c);
                #pragma unroll
                for (int u = 0; u < 4; ++u)
                    #pragma unroll
                    for (int r = 0; r < 4; ++r) {
                        float av = acc[a][u][r];
                        if (av >= thrA) {
                            if (pos < CAP)
                                list[(size_t)grow * CAP + pos] =
                                    make_uint2(__float_as_uint(-2.f * av),
                                               (u32)(strip * 64 + u * 16 + lq * 4 + r));
                            ++pos;
                        }
                    }
            }
        }
    }
}

// ---------------------------------------------------------------- phase 2
// R17/R19 VERBATIM. First list entry hoisted (independent of n; n>=1
// guaranteed). n==1 / unique-margin-survivor fast paths; exact_rb
// (bsum-precomputed, np-bit-exact) for ties; full scan for n>CAP overflow.
__launch_bounds__(256)
__global__ void phase2(const float* __restrict__ x, const float* __restrict__ emb,
                       const u32* __restrict__ cnt, const uint2* __restrict__ list,
                       const float* __restrict__ bsum,
                       float* __restrict__ outq, float* __restrict__ outp) {
    __shared__ float xs[4][DDIM];
    const int wid = threadIdx.x >> 6;
    const int row = blockIdx.x * 4 + wid;
    const int L   = threadIdx.x & 63;

    u32 n = cnt[row];
    uint2 e0 = list[(size_t)row * CAP];   // hoisted: independent of n
    u32 kstar;

    if (n == 1) {
        kstar = e0.y;                     // unique candidate: no rescue needed
    } else {
        bool scan_all = (n > CAP);
        bool resolved = false;
        float vv = INFINITY; u32 kk = 0;
        bool surv = false;
        if (!scan_all) {
            if (L < (int)n) {
                uint2 e = (L == 0) ? e0 : list[(size_t)row * CAP + L];
                vv = __uint_as_float(e.x); kk = e.y;
            }
            float mv = vv;
            #pragma unroll
            for (int o = 32; o; o >>= 1) mv = fminf(mv, __shfl_xor(mv, o, 64));
            surv = (L < (int)n) && (vv <= mv + MARGIN2);
            u64 bal = __ballot(surv);
            if (__popcll(bal) == 1) {          // unique margin-survivor = exact winner
                kstar = __shfl(kk, (int)(__ffsll(bal) - 1), 64);
                resolved = true;
            }
        }
        if (!resolved) {
            float4 v = ((const float4*)(x + (size_t)row * DDIM))[L];
            *(float4*)&xs[wid][L * 4] = v;
            double s = (double)v.x * v.x + (double)v.y * v.y + (double)v.z * v.z + (double)v.w * v.w;
            #pragma unroll
            for (int o = 32; o; o >>= 1) s += __shfl_xor(s, o, 64);
            float A = (float)s;

            u64 key = 0xFFFFFFFFFFFFFFFFull;
            if (!scan_all) {
                if (surv) {
                    float r = exact_rb(xs[wid], A, emb + (size_t)kk * DDIM, bsum[kk]);
                    key = ((u64)fkey(r) << 32) | (u64)kk;
                }
            } else {
                for (int c = 0; c < KCAND / 64; ++c) {
                    u32 k = (u32)(c * 64 + L);
                    float r = exact_rb(xs[wid], A, emb + (size_t)k * DDIM, bsum[k]);
                    u64 cand = ((u64)fkey(r) << 32) | (u64)k;
                    key = (cand < key) ? cand : key;
                }
            }
            #pragma unroll
            for (int o = 32; o; o >>= 1) {
                u64 other = __shfl_xor(key, o, 64);
                key = (other < key) ? other : key;
            }
            kstar = (u32)(key & 0xFFFFFFFFull);
        }
    }

    float4 q = ((const float4*)(emb + (size_t)kstar * DDIM))[L];
    ((float4*)(outq + (size_t)row * DDIM))[L] = q;
    if (L == 0) outp[row] = (float)kstar;
}

// ---------------------------------------------------------------- launch
extern "C" void kernel_launch(void* const* d_in, const int* in_sizes, int n_in,
                              void* d_out, int out_size, void* d_ws, size_t ws_size,
                              hipStream_t stream) {
    const float* x   = (const float*)d_in[0];   // [65536, 256] fp32
    const float* emb = (const float*)d_in[1];   // [4096, 256] fp32
    float* outq = (float*)d_out;                      // [65536,256]
    float* outp = outq + (size_t)NROWS * DDIM;        // [65536]

    char* ws = (char*)d_ws;
    u32*   ebf  = (u32*)ws;                           // 2 MB (strip-major bf16)
    u32*   cnt  = (u32*)(ws + (2u << 20));            // 256 KB @2MB (zeroed in-kernel)
    float* bsum = (float*)(ws + (2u << 20) + (256u << 10));   // 16 KB
    uint2* list = (uint2*)(ws + (3u << 20));          // 24 MB (total 27 MB)

    convert_e<<<512, 256, 0, stream>>>(emb, ebf);
    bsum_k<<<KCAND / 256, 256, 0, stream>>>(emb, bsum);
    phase1<<<NROWS / ROWS_PB, 256, 0, stream>>>(x, ebf, cnt, list);
    phase2<<<NROWS / 4, 256, 0, stream>>>(x, emb, cnt, list, bsum, outq, outp);
}

// Round 21
// 375.074 us; speedup vs baseline: 1.0147x; 1.0004x over previous
//
#include <hip/hip_runtime.h>
#include <hip/hip_bf16.h>
#include <stdint.h>

#define NROWS 65536   // B*S = 16*4096
#define DDIM  256
#define KCAND 4096
#define CAP   48      // per-row candidate list slots (session-best value)
#define MARGIN1 5.2e-4f // phase-1 collect margin (worst-case bound 4.9e-4)
#define MARGIN2 8e-4f   // phase-2 prune margin

#define ROWS_PB 128   // rows per phase-1 block

typedef __bf16 bf16x8 __attribute__((ext_vector_type(8)));
typedef float  f32x4  __attribute__((ext_vector_type(4)));
typedef unsigned int u32;
typedef unsigned long long u64;

__device__ __forceinline__ u32 f2bf_u(float f) {
    u32 u = __float_as_uint(f);
    u += 0x7fffu + ((u >> 16) & 1u);
    return u >> 16;
}
__device__ __forceinline__ u32 pack2(float lo, float hi) { return f2bf_u(lo) | (f2bf_u(hi) << 16); }
__device__ __forceinline__ u32 fkey(float f) {
    u32 u = __float_as_uint(f);
    return (u & 0x80000000u) ? ~u : (u | 0x80000000u);
}
__device__ __forceinline__ float funkey(u32 k) {
    u32 u = (k & 0x80000000u) ? (k ^ 0x80000000u) : ~k;
    return __uint_as_float(u);
}
__device__ __forceinline__ float vmax4(f32x4 v) {
    return fmaxf(fmaxf(v[0], v[1]), fmaxf(v[2], v[3]));
}

// np-semantics exact distance with PRECOMPUTED b = fl(sequential fmaf sum e^2):
// r = fl(fl(A + b) - acc), acc = sequential ascending-d fmaf(2x,e). Bit-identical
// to the scalar np order (HW-validated R7-R20).
__device__ __forceinline__ float exact_rb(const float* __restrict__ xr, float A,
                                          const float* __restrict__ er, float b) {
    float acc = 0.f;
    #pragma unroll 8
    for (int q = 0; q < DDIM / 4; ++q) {
        float4 e  = ((const float4*)er)[q];
        float4 xv = ((const float4*)xr)[q];
        acc = fmaf(2.0f * xv.x, e.x, acc);
        acc = fmaf(2.0f * xv.y, e.y, acc);
        acc = fmaf(2.0f * xv.z, e.z, acc);
        acc = fmaf(2.0f * xv.w, e.w, acc);
    }
    return (A + b) - acc;
}

// ---------------------------------------------------------------- prep (fused)
// Blocks 0..511: convert_e — ebf strip-major: frag(s,kc,u) = 1KB block at
//   ((s*8+kc)*4+u)*1024; lane L's 16B at +L*16 holds cand = s*64+u*16+(L&15),
//   k = kc*32+(L>>4)*8 (8 bf16).
// Blocks 512..527: bsum_k — b_k = sequential ascending-d fmaf(e,e) chain,
//   EXACT np order (one thread per candidate).
// Both read only emb, write disjoint buffers, no ordering between them ->
// safe to fuse (saves one graph dispatch slot).
__launch_bounds__(256)
__global__ void prep(const float* __restrict__ e, u32* __restrict__ ebf,
                     float* __restrict__ bsum) {
    if (blockIdx.x < 512) {
        int T = blockIdx.x * 256 + threadIdx.x;   // 131072 = 64 s * 8 kc * 4 u * 64 L
        int L = T & 63, u = (T >> 6) & 3, kc = (T >> 8) & 7, s = T >> 11;
        int cand = s * 64 + u * 16 + (L & 15);
        int k0 = kc * 32 + (L >> 4) * 8;
        const float4* src = (const float4*)(e + (size_t)cand * DDIM + k0);
        float4 a = src[0], b = src[1];
        uint4 o;
        o.x = pack2(a.x, a.y); o.y = pack2(a.z, a.w);
        o.z = pack2(b.x, b.y); o.w = pack2(b.z, b.w);
        ((uint4*)ebf)[T] = o;
    } else {
        int k = (blockIdx.x - 512) * 256 + threadIdx.x;   // 16 blocks x 256 = 4096
        const float4* er = (const float4*)(e + (size_t)k * DDIM);
        float b = 0.f;
        #pragma unroll 8
        for (int q = 0; q < DDIM / 4; ++q) {
            float4 v = er[q];
            b = fmaf(v.x, v.x, b);
            b = fmaf(v.y, v.y, b);
            b = fmaf(v.z, v.z, b);
            b = fmaf(v.w, v.w, b);
        }
        bsum[k] = b;
    }
}

// ---------------------------------------------------------------- phase 1
// SESSION-BEST ARTIFACT (217us phase1, measured R17/R19/R20) + in-kernel cnt
// zeroing (R20: block-exclusive rows, plain store before first barrier).
// Frag-major x tile: frag(a,kc) = 1KB block at (a*8+kc)*1024; lane L's 16B at
// +L*16 holds x[a*16+(L&15)][kc*32+(L>>4)*8..+8]. Conflict-free (1.8M),
// compile-time offsets. REGISTER WALL: acc = 128 AGPR; VGPR must stay <= 128
// for 2 blocks/CU -> (256,2) enforces. Do not touch structure.
__launch_bounds__(256, 2)
__global__ void phase1(const float* __restrict__ x, const u32* __restrict__ ebf,
                       u32* __restrict__ cnt, uint2* __restrict__ list) {
    __shared__ u32 lxd[16384];           // 64KB frag-major x tile
    __shared__ u32 rowBestK[ROWS_PB];    // fkey(row acc-max), monotone under atomicMax

    const int tid = threadIdx.x;
    const int rowBase = blockIdx.x * ROWS_PB;
    if (tid < ROWS_PB) {
        rowBestK[tid] = 0x007FFFFFu;     // fkey(-inf)
        cnt[rowBase + tid] = 0;          // block-exclusive rows: self-zeroed
    }

    // stage x tile once: fp32 -> bf16, FRAG-MAJOR scatter
    {
        const float4* x4 = (const float4*)(x + (size_t)rowBase * DDIM);
        #pragma unroll
        for (int j = 0; j < 32; ++j) {
            int idx = j * 256 + tid;          // 0..8191 float4 chunks
            int r = idx >> 6, c4 = idx & 63;
            float4 v = x4[idx];
            int a = r >> 4, ln = r & 15;
            int kc = c4 >> 3, lq = (c4 & 7) >> 1;
            int dstb = (a * 8 + kc) * 1024 + (ln + lq * 16) * 16 + 8 * (c4 & 1);
            *(uint2*)((char*)lxd + dstb) = make_uint2(pack2(v.x, v.y), pack2(v.z, v.w));
        }
    }
    __syncthreads();

    const int L = tid & 63;
    const int w = __builtin_amdgcn_readfirstlane(tid >> 6);   // force SGPR
    const int lq = L >> 4, ln = L & 15;
    const int vL = L << 4;                                     // lane byte offset in frag

    const char* ebc_w = (const char*)ebf + (size_t)w * 32768;

    auto loadB = [&](int it_, int kc_, bf16x8* dst) {
        const char* kb = ebc_w + (size_t)it_ * 131072 + kc_ * 4096;
        #pragma unroll
        for (int u = 0; u < 4; ++u)
            dst[u] = *(const bf16x8*)(kb + u * 1024 + vL);
    };

    // fa: one VGPR address (lane base), all frag offsets compile-time (< 64KB)
    const char* pa = (const char*)lxd + vL;

    bf16x8 bb[2][4];
    f32x4 acc[8][4];
    const f32x4 Z4 = {0.f, 0.f, 0.f, 0.f};

    // ---- PRE-PASS: it=0 maxes only, seeds rowBestK ----
    loadB(0, 0, bb[0]);
    #pragma unroll
    for (int kc = 0; kc < 8; ++kc) {
        if (kc < 7) loadB(0, kc + 1, bb[(kc + 1) & 1]);
        #pragma unroll
        for (int a = 0; a < 8; ++a) {
            bf16x8 fa = *(const bf16x8*)(pa + (a * 8 + kc) * 1024);
            #pragma unroll
            for (int u = 0; u < 4; ++u)
                acc[a][u] = (kc == 0)
                    ? __builtin_amdgcn_mfma_f32_16x16x32_bf16(bb[0][u], fa, Z4, 0, 0, 0)
                    : __builtin_amdgcn_mfma_f32_16x16x32_bf16(bb[kc & 1][u], fa, acc[a][u], 0, 0, 0);
        }
    }
    #pragma unroll
    for (int a = 0; a < 8; ++a) {
        float lmax = fmaxf(fmaxf(vmax4(acc[a][0]), vmax4(acc[a][1])),
                           fmaxf(vmax4(acc[a][2]), vmax4(acc[a][3])));
        float m = fmaxf(lmax, __shfl_xor(lmax, 16, 64));
        m = fmaxf(m, __shfl_xor(m, 32, 64));
        if (lq == 0) atomicMax(&rowBestK[a * 16 + ln], fkey(m));
    }
    __syncthreads();   // seeds visible before any collection

    // ---- MAIN LOOP: it=0..15 with collection ----
    loadB(0, 0, bb[0]);   // re-load (L1/L2-hot)
    #pragma unroll 1
    for (int it = 0; it < 16; ++it) {
        // kc = 0 peeled: accumulator init via zero C-operand
        {
            loadB(it, 1, bb[1]);
            #pragma unroll
            for (int a = 0; a < 8; ++a) {
                bf16x8 fa = *(const bf16x8*)(pa + (a * 8) * 1024);
                #pragma unroll
                for (int u = 0; u < 4; ++u)
                    acc[a][u] = __builtin_amdgcn_mfma_f32_16x16x32_bf16(bb[0][u], fa, Z4, 0, 0, 0);
            }
        }
        #pragma unroll
        for (int kc = 1; kc < 8; ++kc) {
            int g = it * 8 + kc;
            if (g < 127) { int gn = g + 1; loadB(gn >> 3, gn & 7, bb[(kc + 1) & 1]); }
            #pragma unroll
            for (int a = 0; a < 8; ++a) {
                bf16x8 fa = *(const bf16x8*)(pa + (a * 8 + kc) * 1024);
                #pragma unroll
                for (int u = 0; u < 4; ++u)
                    acc[a][u] = __builtin_amdgcn_mfma_f32_16x16x32_bf16(bb[kc & 1][u], fa, acc[a][u], 0, 0, 0);
            }
        }

        // epilogue for this strip (cands strip*64 .. +64), row-in-lane layout
        int strip = it * 4 + w;
        u32 seen[8];
        #pragma unroll
        for (int a = 0; a < 8; ++a) seen[a] = rowBestK[a * 16 + ln];   // broadcast reads, stale OK

        #pragma unroll
        for (int a = 0; a < 8; ++a) {
            float lmax = fmaxf(fmaxf(vmax4(acc[a][0]), vmax4(acc[a][1])),
                               fmaxf(vmax4(acc[a][2]), vmax4(acc[a][3])));
            float m = fmaxf(lmax, __shfl_xor(lmax, 16, 64));
            m = fmaxf(m, __shfl_xor(m, 32, 64));
            if (lq == 0) atomicMax(&rowBestK[a * 16 + ln], fkey(m));   // fire-and-forget
            float eff  = fmaxf(m, funkey(seen[a]));   // own strip folded in via register
            float thrA = eff - 0.5f * MARGIN1;        // acc-space threshold
            if (__ballot(lmax >= thrA)) {             // usually nothing fires
                int c = 0;
                #pragma unroll
                for (int u = 0; u < 4; ++u)
                    #pragma unroll
                    for (int r = 0; r < 4; ++r)
                        c += (acc[a][u][r] >= thrA) ? 1 : 0;
                int p = c, t;
                t = __shfl_up(p, 16, 64); if (lq >= 1) p += t;
                t = __shfl_up(p, 32, 64); if (lq >= 2) p += t;
                int grow = rowBase + a * 16 + ln;
                u32 base = 0;
                if (lq == 3 && p > 0) base = atomicAdd(&cnt[grow], (u32)p);  // 16 distinct rows
                base = __shfl(base, 48 + ln, 64);     // broadcast from lq==3 lane of this row
                u32 pos = base + (u32)(p - c);
                #pragma unroll
                for (int u = 0; u < 4; ++u)
                    #pragma unroll
                    for (int r = 0; r < 4; ++r) {
                        float av = acc[a][u][r];
                        if (av >= thrA) {
                            if (pos < CAP)
                                list[(size_t)grow * CAP + pos] =
                                    make_uint2(__float_as_uint(-2.f * av),
                                               (u32)(strip * 64 + u * 16 + lq * 4 + r));
                            ++pos;
                        }
                    }
            }
        }
    }
}

// ---------------------------------------------------------------- phase 2
// SESSION-BEST VERBATIM. First list entry hoisted (independent of n; n>=1
// guaranteed). n==1 / unique-margin-survivor fast paths; exact_rb
// (bsum-precomputed, np-bit-exact) for ties; full scan for n>CAP overflow.
__launch_bounds__(256)
__global__ void phase2(const float* __restrict__ x, const float* __restrict__ emb,
                       const u32* __restrict__ cnt, const uint2* __restrict__ list,
                       const float* __restrict__ bsum,
                       float* __restrict__ outq, float* __restrict__ outp) {
    __shared__ float xs[4][DDIM];
    const int wid = threadIdx.x >> 6;
    const int row = blockIdx.x * 4 + wid;
    const int L   = threadIdx.x & 63;

    u32 n = cnt[row];
    uint2 e0 = list[(size_t)row * CAP];   // hoisted: independent of n
    u32 kstar;

    if (n == 1) {
        kstar = e0.y;                     // unique candidate: no rescue needed
    } else {
        bool scan_all = (n > CAP);
        bool resolved = false;
        float vv = INFINITY; u32 kk = 0;
        bool surv = false;
        if (!scan_all) {
            if (L < (int)n) {
                uint2 e = (L == 0) ? e0 : list[(size_t)row * CAP + L];
                vv = __uint_as_float(e.x); kk = e.y;
            }
            float mv = vv;
            #pragma unroll
            for (int o = 32; o; o >>= 1) mv = fminf(mv, __shfl_xor(mv, o, 64));
            surv = (L < (int)n) && (vv <= mv + MARGIN2);
            u64 bal = __ballot(surv);
            if (__popcll(bal) == 1) {          // unique margin-survivor = exact winner
                kstar = __shfl(kk, (int)(__ffsll(bal) - 1), 64);
                resolved = true;
            }
        }
        if (!resolved) {
            float4 v = ((const float4*)(x + (size_t)row * DDIM))[L];
            *(float4*)&xs[wid][L * 4] = v;
            double s = (double)v.x * v.x + (double)v.y * v.y + (double)v.z * v.z + (double)v.w * v.w;
            #pragma unroll
            for (int o = 32; o; o >>= 1) s += __shfl_xor(s, o, 64);
            float A = (float)s;

            u64 key = 0xFFFFFFFFFFFFFFFFull;
            if (!scan_all) {
                if (surv) {
                    float r = exact_rb(xs[wid], A, emb + (size_t)kk * DDIM, bsum[kk]);
                    key = ((u64)fkey(r) << 32) | (u64)kk;
                }
            } else {
                for (int c = 0; c < KCAND / 64; ++c) {
                    u32 k = (u32)(c * 64 + L);
                    float r = exact_rb(xs[wid], A, emb + (size_t)k * DDIM, bsum[k]);
                    u64 cand = ((u64)fkey(r) << 32) | (u64)k;
                    key = (cand < key) ? cand : key;
                }
            }
            #pragma unroll
            for (int o = 32; o; o >>= 1) {
                u64 other = __shfl_xor(key, o, 64);
                key = (other < key) ? other : key;
            }
            kstar = (u32)(key & 0xFFFFFFFFull);
        }
    }

    float4 q = ((const float4*)(emb + (size_t)kstar * DDIM))[L];
    ((float4*)(outq + (size_t)row * DDIM))[L] = q;
    if (L == 0) outp[row] = (float)kstar;
}

// ---------------------------------------------------------------- launch
extern "C" void kernel_launch(void* const* d_in, const int* in_sizes, int n_in,
                              void* d_out, int out_size, void* d_ws, size_t ws_size,
                              hipStream_t stream) {
    const float* x   = (const float*)d_in[0];   // [65536, 256] fp32
    const float* emb = (const float*)d_in[1];   // [4096, 256] fp32
    float* outq = (float*)d_out;                      // [65536,256]
    float* outp = outq + (size_t)NROWS * DDIM;        // [65536]

    char* ws = (char*)d_ws;
    u32*   ebf  = (u32*)ws;                           // 2 MB (strip-major bf16)
    u32*   cnt  = (u32*)(ws + (2u << 20));            // 256 KB @2MB (zeroed in-kernel)
    float* bsum = (float*)(ws + (2u << 20) + (256u << 10));   // 16 KB
    uint2* list = (uint2*)(ws + (3u << 20));          // 24 MB (total 27 MB)

    prep<<<528, 256, 0, stream>>>(emb, ebf, bsum);
    phase1<<<NROWS / ROWS_PB, 256, 0, stream>>>(x, ebf, cnt, list);
    phase2<<<NROWS / 4, 256, 0, stream>>>(x, emb, cnt, list, bsum, outq, outp);
}

// Round 22
// 374.363 us; speedup vs baseline: 1.0167x; 1.0019x over previous
//
#include <hip/hip_runtime.h>
#include <hip/hip_bf16.h>
#include <stdint.h>

#define NROWS 65536   // B*S = 16*4096
#define DDIM  256
#define KCAND 4096
#define CAP   48      // per-row candidate list slots (session-best value)
#define MARGIN1 5.2e-4f // phase-1 collect margin (worst-case bound 4.9e-4)
#define MARGIN2 8e-4f   // phase-2 prune margin

#define ROWS_PB 128   // rows per phase-1 block

typedef __bf16 bf16x8 __attribute__((ext_vector_type(8)));
typedef float  f32x4  __attribute__((ext_vector_type(4)));
typedef unsigned int u32;
typedef unsigned long long u64;

__device__ __forceinline__ u32 f2bf_u(float f) {
    u32 u = __float_as_uint(f);
    u += 0x7fffu + ((u >> 16) & 1u);
    return u >> 16;
}
__device__ __forceinline__ u32 pack2(float lo, float hi) { return f2bf_u(lo) | (f2bf_u(hi) << 16); }
__device__ __forceinline__ u32 fkey(float f) {
    u32 u = __float_as_uint(f);
    return (u & 0x80000000u) ? ~u : (u | 0x80000000u);
}
__device__ __forceinline__ float funkey(u32 k) {
    u32 u = (k & 0x80000000u) ? (k ^ 0x80000000u) : ~k;
    return __uint_as_float(u);
}
__device__ __forceinline__ float vmax4(f32x4 v) {
    return fmaxf(fmaxf(v[0], v[1]), fmaxf(v[2], v[3]));
}

// np-semantics exact distance with PRECOMPUTED b = fl(sequential fmaf sum e^2):
// r = fl(fl(A + b) - acc), acc = sequential ascending-d fmaf(2x,e). Bit-identical
// to the scalar np order (HW-validated R7-R21).
__device__ __forceinline__ float exact_rb(const float* __restrict__ xr, float A,
                                          const float* __restrict__ er, float b) {
    float acc = 0.f;
    #pragma unroll 8
    for (int q = 0; q < DDIM / 4; ++q) {
        float4 e  = ((const float4*)er)[q];
        float4 xv = ((const float4*)xr)[q];
        acc = fmaf(2.0f * xv.x, e.x, acc);
        acc = fmaf(2.0f * xv.y, e.y, acc);
        acc = fmaf(2.0f * xv.z, e.z, acc);
        acc = fmaf(2.0f * xv.w, e.w, acc);
    }
    return (A + b) - acc;
}

// ---------------------------------------------------------------- prep (fused)
// Blocks 0..511: convert_e — ebf strip-major: frag(s,kc,u) = 1KB block at
//   ((s*8+kc)*4+u)*1024; lane L's 16B at +L*16 holds cand = s*64+u*16+(L&15),
//   k = kc*32+(L>>4)*8 (8 bf16).
// Blocks 512..527: bsum_k — b_k = sequential ascending-d fmaf(e,e) chain,
//   EXACT np order (one thread per candidate).
__launch_bounds__(256)
__global__ void prep(const float* __restrict__ e, u32* __restrict__ ebf,
                     float* __restrict__ bsum) {
    if (blockIdx.x < 512) {
        int T = blockIdx.x * 256 + threadIdx.x;   // 131072 = 64 s * 8 kc * 4 u * 64 L
        int L = T & 63, u = (T >> 6) & 3, kc = (T >> 8) & 7, s = T >> 11;
        int cand = s * 64 + u * 16 + (L & 15);
        int k0 = kc * 32 + (L >> 4) * 8;
        const float4* src = (const float4*)(e + (size_t)cand * DDIM + k0);
        float4 a = src[0], b = src[1];
        uint4 o;
        o.x = pack2(a.x, a.y); o.y = pack2(a.z, a.w);
        o.z = pack2(b.x, b.y); o.w = pack2(b.z, b.w);
        ((uint4*)ebf)[T] = o;
    } else {
        int k = (blockIdx.x - 512) * 256 + threadIdx.x;   // 16 blocks x 256 = 4096
        const float4* er = (const float4*)(e + (size_t)k * DDIM);
        float b = 0.f;
        #pragma unroll 8
        for (int q = 0; q < DDIM / 4; ++q) {
            float4 v = er[q];
            b = fmaf(v.x, v.x, b);
            b = fmaf(v.y, v.y, b);
            b = fmaf(v.z, v.z, b);
            b = fmaf(v.w, v.w, b);
        }
        bsum[k] = b;
    }
}

// ---------------------------------------------------------------- phase 1
// SESSION-BEST ARTIFACT (217us, measured R17/R19/R20/R21) + in-kernel cnt
// zeroing (block-exclusive rows, plain store before first barrier).
// Frag-major x tile: frag(a,kc) = 1KB block at (a*8+kc)*1024; lane L's 16B at
// +L*16 holds x[a*16+(L&15)][kc*32+(L>>4)*8..+8]. Conflict-free (1.8M),
// compile-time offsets. REGISTER WALL: acc = 128 AGPR; VGPR must stay <= 128
// for 2 blocks/CU -> (256,2) enforces. Do not touch structure.
__launch_bounds__(256, 2)
__global__ void phase1(const float* __restrict__ x, const u32* __restrict__ ebf,
                       u32* __restrict__ cnt, uint2* __restrict__ list) {
    __shared__ u32 lxd[16384];           // 64KB frag-major x tile
    __shared__ u32 rowBestK[ROWS_PB];    // fkey(row acc-max), monotone under atomicMax

    const int tid = threadIdx.x;
    const int rowBase = blockIdx.x * ROWS_PB;
    if (tid < ROWS_PB) {
        rowBestK[tid] = 0x007FFFFFu;     // fkey(-inf)
        cnt[rowBase + tid] = 0;          // block-exclusive rows: self-zeroed
    }

    // stage x tile once: fp32 -> bf16, FRAG-MAJOR scatter
    {
        const float4* x4 = (const float4*)(x + (size_t)rowBase * DDIM);
        #pragma unroll
        for (int j = 0; j < 32; ++j) {
            int idx = j * 256 + tid;          // 0..8191 float4 chunks
            int r = idx >> 6, c4 = idx & 63;
            float4 v = x4[idx];
            int a = r >> 4, ln = r & 15;
            int kc = c4 >> 3, lq = (c4 & 7) >> 1;
            int dstb = (a * 8 + kc) * 1024 + (ln + lq * 16) * 16 + 8 * (c4 & 1);
            *(uint2*)((char*)lxd + dstb) = make_uint2(pack2(v.x, v.y), pack2(v.z, v.w));
        }
    }
    __syncthreads();

    const int L = tid & 63;
    const int w = __builtin_amdgcn_readfirstlane(tid >> 6);   // force SGPR
    const int lq = L >> 4, ln = L & 15;
    const int vL = L << 4;                                     // lane byte offset in frag

    const char* ebc_w = (const char*)ebf + (size_t)w * 32768;

    auto loadB = [&](int it_, int kc_, bf16x8* dst) {
        const char* kb = ebc_w + (size_t)it_ * 131072 + kc_ * 4096;
        #pragma unroll
        for (int u = 0; u < 4; ++u)
            dst[u] = *(const bf16x8*)(kb + u * 1024 + vL);
    };

    // fa: one VGPR address (lane base), all frag offsets compile-time (< 64KB)
    const char* pa = (const char*)lxd + vL;

    bf16x8 bb[2][4];
    f32x4 acc[8][4];
    const f32x4 Z4 = {0.f, 0.f, 0.f, 0.f};

    // ---- PRE-PASS: it=0 maxes only, seeds rowBestK ----
    loadB(0, 0, bb[0]);
    #pragma unroll
    for (int kc = 0; kc < 8; ++kc) {
        if (kc < 7) loadB(0, kc + 1, bb[(kc + 1) & 1]);
        #pragma unroll
        for (int a = 0; a < 8; ++a) {
            bf16x8 fa = *(const bf16x8*)(pa + (a * 8 + kc) * 1024);
            #pragma unroll
            for (int u = 0; u < 4; ++u)
                acc[a][u] = (kc == 0)
                    ? __builtin_amdgcn_mfma_f32_16x16x32_bf16(bb[0][u], fa, Z4, 0, 0, 0)
                    : __builtin_amdgcn_mfma_f32_16x16x32_bf16(bb[kc & 1][u], fa, acc[a][u], 0, 0, 0);
        }
    }
    #pragma unroll
    for (int a = 0; a < 8; ++a) {
        float lmax = fmaxf(fmaxf(vmax4(acc[a][0]), vmax4(acc[a][1])),
                           fmaxf(vmax4(acc[a][2]), vmax4(acc[a][3])));
        float m = fmaxf(lmax, __shfl_xor(lmax, 16, 64));
        m = fmaxf(m, __shfl_xor(m, 32, 64));
        if (lq == 0) atomicMax(&rowBestK[a * 16 + ln], fkey(m));
    }
    __syncthreads();   // seeds visible before any collection

    // ---- MAIN LOOP: it=0..15 with collection ----
    loadB(0, 0, bb[0]);   // re-load (L1/L2-hot)
    #pragma unroll 1
    for (int it = 0; it < 16; ++it) {
        // kc = 0 peeled: accumulator init via zero C-operand
        {
            loadB(it, 1, bb[1]);
            #pragma unroll
            for (int a = 0; a < 8; ++a) {
                bf16x8 fa = *(const bf16x8*)(pa + (a * 8) * 1024);
                #pragma unroll
                for (int u = 0; u < 4; ++u)
                    acc[a][u] = __builtin_amdgcn_mfma_f32_16x16x32_bf16(bb[0][u], fa, Z4, 0, 0, 0);
            }
        }
        #pragma unroll
        for (int kc = 1; kc < 8; ++kc) {
            int g = it * 8 + kc;
            if (g < 127) { int gn = g + 1; loadB(gn >> 3, gn & 7, bb[(kc + 1) & 1]); }
            #pragma unroll
            for (int a = 0; a < 8; ++a) {
                bf16x8 fa = *(const bf16x8*)(pa + (a * 8 + kc) * 1024);
                #pragma unroll
                for (int u = 0; u < 4; ++u)
                    acc[a][u] = __builtin_amdgcn_mfma_f32_16x16x32_bf16(bb[kc & 1][u], fa, acc[a][u], 0, 0, 0);
            }
        }

        // epilogue for this strip (cands strip*64 .. +64), row-in-lane layout
        int strip = it * 4 + w;
        u32 seen[8];
        #pragma unroll
        for (int a = 0; a < 8; ++a) seen[a] = rowBestK[a * 16 + ln];   // broadcast reads, stale OK

        #pragma unroll
        for (int a = 0; a < 8; ++a) {
            float lmax = fmaxf(fmaxf(vmax4(acc[a][0]), vmax4(acc[a][1])),
                               fmaxf(vmax4(acc[a][2]), vmax4(acc[a][3])));
            float m = fmaxf(lmax, __shfl_xor(lmax, 16, 64));
            m = fmaxf(m, __shfl_xor(m, 32, 64));
            if (lq == 0) atomicMax(&rowBestK[a * 16 + ln], fkey(m));   // fire-and-forget
            float eff  = fmaxf(m, funkey(seen[a]));   // own strip folded in via register
            float thrA = eff - 0.5f * MARGIN1;        // acc-space threshold
            if (__ballot(lmax >= thrA)) {             // usually nothing fires
                int c = 0;
                #pragma unroll
                for (int u = 0; u < 4; ++u)
                    #pragma unroll
                    for (int r = 0; r < 4; ++r)
                        c += (acc[a][u][r] >= thrA) ? 1 : 0;
                int p = c, t;
                t = __shfl_up(p, 16, 64); if (lq >= 1) p += t;
                t = __shfl_up(p, 32, 64); if (lq >= 2) p += t;
                int grow = rowBase + a * 16 + ln;
                u32 base = 0;
                if (lq == 3 && p > 0) base = atomicAdd(&cnt[grow], (u32)p);  // 16 distinct rows
                base = __shfl(base, 48 + ln, 64);     // broadcast from lq==3 lane of this row
                u32 pos = base + (u32)(p - c);
                #pragma unroll
                for (int u = 0; u < 4; ++u)
                    #pragma unroll
                    for (int r = 0; r < 4; ++r) {
                        float av = acc[a][u][r];
                        if (av >= thrA) {
                            if (pos < CAP)
                                list[(size_t)grow * CAP + pos] =
                                    make_uint2(__float_as_uint(-2.f * av),
                                               (u32)(strip * 64 + u * 16 + lq * 4 + r));
                            ++pos;
                        }
                    }
            }
        }
    }
}

// ---------------------------------------------------------------- phase 2
// SESSION-BEST VERBATIM. First list entry hoisted (independent of n; n>=1
// guaranteed). n==1 / unique-margin-survivor fast paths; exact_rb
// (bsum-precomputed, np-bit-exact) for ties; full scan for n>CAP overflow.
__launch_bounds__(256)
__global__ void phase2(const float* __restrict__ x, const float* __restrict__ emb,
                       const u32* __restrict__ cnt, const uint2* __restrict__ list,
                       const float* __restrict__ bsum,
                       float* __restrict__ outq, float* __restrict__ outp) {
    __shared__ float xs[4][DDIM];
    const int wid = threadIdx.x >> 6;
    const int row = blockIdx.x * 4 + wid;
    const int L   = threadIdx.x & 63;

    u32 n = cnt[row];
    uint2 e0 = list[(size_t)row * CAP];   // hoisted: independent of n
    u32 kstar;

    if (n == 1) {
        kstar = e0.y;                     // unique candidate: no rescue needed
    } else {
        bool scan_all = (n > CAP);
        bool resolved = false;
        float vv = INFINITY; u32 kk = 0;
        bool surv = false;
        if (!scan_all) {
            if (L < (int)n) {
                uint2 e = (L == 0) ? e0 : list[(size_t)row * CAP + L];
                vv = __uint_as_float(e.x); kk = e.y;
            }
            float mv = vv;
            #pragma unroll
            for (int o = 32; o; o >>= 1) mv = fminf(mv, __shfl_xor(mv, o, 64));
            surv = (L < (int)n) && (vv <= mv + MARGIN2);
            u64 bal = __ballot(surv);
            if (__popcll(bal) == 1) {          // unique margin-survivor = exact winner
                kstar = __shfl(kk, (int)(__ffsll(bal) - 1), 64);
                resolved = true;
            }
        }
        if (!resolved) {
            float4 v = ((const float4*)(x + (size_t)row * DDIM))[L];
            *(float4*)&xs[wid][L * 4] = v;
            double s = (double)v.x * v.x + (double)v.y * v.y + (double)v.z * v.z + (double)v.w * v.w;
            #pragma unroll
            for (int o = 32; o; o >>= 1) s += __shfl_xor(s, o, 64);
            float A = (float)s;

            u64 key = 0xFFFFFFFFFFFFFFFFull;
            if (!scan_all) {
                if (surv) {
                    float r = exact_rb(xs[wid], A, emb + (size_t)kk * DDIM, bsum[kk]);
                    key = ((u64)fkey(r) << 32) | (u64)kk;
                }
            } else {
                for (int c = 0; c < KCAND / 64; ++c) {
                    u32 k = (u32)(c * 64 + L);
                    float r = exact_rb(xs[wid], A, emb + (size_t)k * DDIM, bsum[k]);
                    u64 cand = ((u64)fkey(r) << 32) | (u64)k;
                    key = (cand < key) ? cand : key;
                }
            }
            #pragma unroll
            for (int o = 32; o; o >>= 1) {
                u64 other = __shfl_xor(key, o, 64);
                key = (other < key) ? other : key;
            }
            kstar = (u32)(key & 0xFFFFFFFFull);
        }
    }

    float4 q = ((const float4*)(emb + (size_t)kstar * DDIM))[L];
    ((float4*)(outq + (size_t)row * DDIM))[L] = q;
    if (L == 0) outp[row] = (float)kstar;
}

// ---------------------------------------------------------------- launch
extern "C" void kernel_launch(void* const* d_in, const int* in_sizes, int n_in,
                              void* d_out, int out_size, void* d_ws, size_t ws_size,
                              hipStream_t stream) {
    const float* x   = (const float*)d_in[0];   // [65536, 256] fp32
    const float* emb = (const float*)d_in[1];   // [4096, 256] fp32
    float* outq = (float*)d_out;                      // [65536,256]
    float* outp = outq + (size_t)NROWS * DDIM;        // [65536]

    char* ws = (char*)d_ws;
    u32*   ebf  = (u32*)ws;                           // 2 MB (strip-major bf16)
    u32*   cnt  = (u32*)(ws + (2u << 20));            // 256 KB @2MB (zeroed in-kernel)
    float* bsum = (float*)(ws + (2u << 20) + (256u << 10));   // 16 KB
    uint2* list = (uint2*)(ws + (3u << 20));          // 24 MB (total 27 MB)

    prep<<<528, 256, 0, stream>>>(emb, ebf, bsum);
    phase1<<<NROWS / ROWS_PB, 256, 0, stream>>>(x, ebf, cnt, list);
    phase2<<<NROWS / 4, 256, 0, stream>>>(x, emb, cnt, list, bsum, outq, outp);
}